// Round 1
// 135.748 us; speedup vs baseline: 1.0412x; 1.0412x over previous
//
#include <hip/hip_runtime.h>

typedef unsigned int u32;
typedef unsigned short u16;
typedef float f32x4 __attribute__((ext_vector_type(4)));
typedef short s16x8 __attribute__((ext_vector_type(8)));

#define Bn 512
#define Sn 512
#define Cn 32
#define Dn 512

// ---------- helpers ----------
__device__ __forceinline__ u32 f2bf(float f) {           // fp32 -> bf16 bits, RNE
  u32 u = __float_as_uint(f);
  return (u + 0x7FFFu + ((u >> 16) & 1u)) >> 16;
}
__device__ __forceinline__ float bfval(u32 bits) { return __uint_as_float(bits << 16); }
__device__ __forceinline__ float keyToFloat(u32 k) {     // inverse of order-preserving map
  u32 u = (k & 0x80000000u) ? (k ^ 0x80000000u) : ~k;
  return __uint_as_float(u);
}
// async 16B global->LDS (LDS side must be wave-uniform base + lane*16)
__device__ __forceinline__ void gl2lds16(const void* g, void* l) {
  __builtin_amdgcn_global_load_lds(
      (const __attribute__((address_space(1))) u32*)g,
      (__attribute__((address_space(3))) u32*)l, 16, 0, 0);
}

// ---------- kernel 1: fused prep (blocks 0..1023) + wmix/gates/colsum (blocks 1024..1087)
// prep: exact median per (b,c) via ballot bisection + write xbf[b*32+v][s] bf16
// wmix: WmixT[d][s] = bf16(g1*We[e1][s][d] + g2*We[e2][s][d]), partial colsums
__global__ __launch_bounds__(256) void k_pw(const float* __restrict__ x,
                                            const float* __restrict__ emb,
                                            const float* __restrict__ Wg,
                                            const float* __restrict__ We,
                                            float* __restrict__ med,
                                            u16* __restrict__ xbf,
                                            u16* __restrict__ WmT,
                                            float* __restrict__ cpart) {
  __shared__ float buf[512][17];             // prep view; wmix aliases first 16.6 KB
  __shared__ float ed[8];
  int blk = blockIdx.x;
  int t = threadIdx.x;

  if (blk < 1024) {
    // ================= prep path =================
    int b = blk >> 1, half = blk & 1;
    int vbase = half * 16;
    int w = t >> 6, l = t & 63;
    const float4* xb4 = (const float4*)(x + (size_t)b * Sn * Cn);
    // phase 1: load 512 s x 16 v, all loads issued back-to-back
    float4 f[8];
#pragma unroll
    for (int i = 0; i < 8; ++i)
      f[i] = xb4[((t >> 2) + i * 64) * 8 + half * 4 + (t & 3)];
#pragma unroll
    for (int i = 0; i < 8; ++i) {
      int s = (t >> 2) + i * 64, c0 = (t & 3) * 4;
      buf[s][c0 + 0] = f[i].x; buf[s][c0 + 1] = f[i].y;
      buf[s][c0 + 2] = f[i].z; buf[s][c0 + 3] = f[i].w;
    }
    __syncthreads();
    // phase 2: per-wave keys for columns w*4..w*4+3
    u32 K[4][8];
#pragma unroll
    for (int cc = 0; cc < 4; ++cc)
#pragma unroll
      for (int j = 0; j < 8; ++j) {
        u32 u = __float_as_uint(buf[j * 64 + l][w * 4 + cc]);
        K[cc][j] = (u >> 31) ? ~u : (u | 0x80000000u);
      }
    // phase 3: transposed bf16 write (overlaps bisection's ALU)
    {
      int vl = t >> 4, sb = (t & 15) * 32;
      u16* orow = xbf + ((size_t)(b * 32 + vbase + vl)) * Sn;
#pragma unroll
      for (int cq = 0; cq < 4; ++cq) {
        int cp = (cq + (t & 15)) & 3;        // chunk rotation vs bank conflicts
        u32 pk[4];
#pragma unroll
        for (int jj = 0; jj < 4; ++jj) {
          u32 lo = f2bf(buf[sb + cp * 8 + jj * 2][vl]);
          u32 hi = f2bf(buf[sb + cp * 8 + jj * 2 + 1][vl]);
          pk[jj] = lo | (hi << 16);
        }
        *(uint4*)(orow + sb + cp * 8) = *(uint4*)pk;
      }
    }
    // phase 4: bisection for rank-255/256 mean.
    // ROLLED bit loop (I$-friendly), 4 column-chains interleaved inside each
    // iteration for ILP; K[][] stays constant-indexed -> registers.
    int base = b * 32 + vbase + w * 4;
    u32 a1v[4] = {0u, 0u, 0u, 0u};
#pragma unroll 1
    for (int bit = 31; bit >= 0; --bit) {
      u32 msk = 1u << bit;
#pragma unroll
      for (int cc = 0; cc < 4; ++cc) {
        u32 cand = a1v[cc] | msk;
        int c = 0;
#pragma unroll
        for (int j = 0; j < 8; ++j) c += __popcll(__ballot(K[cc][j] < cand));
        if (c <= 255) a1v[cc] = cand;
      }
    }
#pragma unroll
    for (int cc = 0; cc < 4; ++cc) {
      u32 a1 = a1v[cc];
      int cle = 0;
#pragma unroll
      for (int j = 0; j < 8; ++j) cle += __popcll(__ballot(K[cc][j] <= a1));
      u32 a2;
      if (cle >= 257) {
        a2 = a1;
      } else {
        u32 mn = 0xFFFFFFFFu;
#pragma unroll
        for (int j = 0; j < 8; ++j) {
          u32 k2 = K[cc][j];
          if (k2 > a1 && k2 < mn) mn = k2;
        }
        mn = min(mn, (u32)__shfl_xor((int)mn, 1, 64));
        mn = min(mn, (u32)__shfl_xor((int)mn, 2, 64));
        mn = min(mn, (u32)__shfl_xor((int)mn, 4, 64));
        mn = min(mn, (u32)__shfl_xor((int)mn, 8, 64));
        mn = min(mn, (u32)__shfl_xor((int)mn, 16, 64));
        mn = min(mn, (u32)__shfl_xor((int)mn, 32, 64));
        a2 = mn;
      }
      if (l == 0) med[base + cc] = 0.5f * (keyToFloat(a1) + keyToFloat(a2));
    }
  } else {
    // ================= wmix path =================
    float (*tile)[65] = (float(*)[65])&buf[0][0];   // 64x65 alias
    int bi2 = blk - 1024;                    // 64 blocks: 8 s-tiles x 8 d-tiles
    int si = bi2 & 7, sb = si * 64, db = (bi2 >> 3) * 64;
    // gates: redundant per block
    if (t < 8) {
      float s = 0.f;
#pragma unroll
      for (int j = 0; j < 32; ++j) s += emb[t * 32 + j] * Wg[Dn + j];
      ed[t] = s;
    }
    __syncthreads();
    int i1 = 0;
#pragma unroll
    for (int e = 1; e < 8; ++e) if (ed[e] > ed[i1]) i1 = e;
    int i2 = (i1 == 0) ? 1 : 0;
#pragma unroll
    for (int e = 0; e < 8; ++e) if (e != i1 && ed[e] > ed[i2]) i2 = e;
    float aa = ed[i1], bb = ed[i2];
    float m = fmaxf(aa, bb);
    float ea = __expf(aa - m), eb = __expf(bb - m);
    float inv = 1.f / (ea + eb);
    float g1 = ea * inv, g2 = eb * inv;
    const float* W1 = We + (size_t)i1 * Sn * Dn;
    const float* W2 = We + (size_t)i2 * Sn * Dn;
#pragma unroll
    for (int i = 0; i < 16; ++i) {
      int idx = t + i * 256;
      int sl = idx >> 6, dl = idx & 63;
      int g = (sb + sl) * Dn + db + dl;
      tile[sl][dl] = g1 * W1[g] + g2 * W2[g];
    }
    __syncthreads();
#pragma unroll
    for (int i = 0; i < 16; ++i) {
      int idx = t + i * 256;
      int dl = idx >> 6, sl = idx & 63;
      WmT[(size_t)(db + dl) * Sn + sb + sl] = (u16)f2bf(tile[sl][dl]);
    }
    // partial colsum over this s-tile: 4 threads per d
    {
      int dl = t >> 2, part = t & 3;
      float s = 0.f;
#pragma unroll
      for (int j = 0; j < 16; ++j)
        s += bfval(f2bf(tile[part * 16 + j][dl]));
      s += __shfl_xor(s, 1, 64);
      s += __shfl_xor(s, 2, 64);
      if (part == 0) cpart[si * 512 + db + dl] = s;
    }
  }
}

// ---------- kernel 2: GEMM  out[b][d][v] = sum_s WmT[d][s]*xbf[b*32+v][s] - med*colsum ----
// M=512 (d), N=16384 (b*32+v), K=512 (s). 128x256 tiles, BK=64, 8 waves,
// 3-LDS-buffer depth-2 pipeline with counted vmcnt (T3/T4) + raw s_barrier.
// 256 blocks = exactly 1/CU; XCD-bijective swizzle groups the 4 mb-blocks of
// one n-panel on one XCD (B-panel L2 reuse).
__global__ __launch_bounds__(512) void k_gemm(const u16* __restrict__ WmT,
                                              const u16* __restrict__ xbf,
                                              const float* __restrict__ med,
                                              const float* __restrict__ cpart,
                                              float* __restrict__ out) {
  __shared__ __align__(16) u16 As[3][128 * 64]; // [m][k] per buf, 16B chunks XOR-swizzled
  __shared__ __align__(16) u16 Bs[3][256 * 64]; // [n][k] per buf
  __shared__ float csum[512];
  int g = blockIdx.x;
  int xcd = g & 7, slot = g >> 3;          // 256 = 8 XCDs x 32 slots (bijective)
  int nb = xcd * 8 + (slot >> 2);          // 64 n-panels, 8 consecutive per XCD
  int mb = slot & 3;                       // 4 m-panels share one n-panel on one XCD
  int t = threadIdx.x, w = t >> 6, l = t & 63;
  int mh = (w & 1) * 64, nh = (w >> 1) * 64;  // 2x4 wave grid, 64x64 per wave
  int lane16 = l & 15, q = l >> 4;
  // reduce colsum partials into LDS (visible after prologue barrier)
  {
    float s = 0.f;
#pragma unroll
    for (int j = 0; j < 8; ++j) s += cpart[j * 512 + t];
    csum[t] = s;
  }
  const u16* Ab = WmT + (size_t)(mb * 128) * Sn;
  const u16* Bb = xbf + (size_t)(nb * 256) * Sn;
  int r0 = t >> 3, c0 = t & 7;

  // stage one 64-wide K chunk of A (128 rows) + B (256 rows): 6 x 16B per thread
#define STAGE(ch, bf_) do {                                                      \
    int k0 = (ch) * 64;                                                          \
    _Pragma("unroll")                                                            \
    for (int i = 0; i < 2; ++i) {                                                \
      int r = r0 + i * 64;                                                       \
      int gc = c0 ^ (r & 7);                                                     \
      gl2lds16(Ab + (size_t)r * Sn + k0 + gc * 8,                                \
               (char*)As[bf_] + t * 16 + i * 8192);                              \
    }                                                                            \
    _Pragma("unroll")                                                            \
    for (int i = 0; i < 4; ++i) {                                                \
      int r = r0 + i * 64;                                                       \
      int gc = c0 ^ (r & 7);                                                     \
      gl2lds16(Bb + (size_t)r * Sn + k0 + gc * 8,                                \
               (char*)Bs[bf_] + t * 16 + i * 8192);                              \
    }                                                                            \
  } while (0)

  f32x4 acc[4][4] = {};
  STAGE(0, 0);
  STAGE(1, 1);
  asm volatile("s_waitcnt lgkmcnt(0)" ::: "memory");  // csum ds_writes drained
  asm volatile("s_waitcnt vmcnt(6)" ::: "memory");    // own stage-0 loads done
  __builtin_amdgcn_s_barrier();
  asm volatile("" ::: "memory");
#pragma unroll
  for (int ch = 0; ch < 8; ++ch) {
    int cur = ch % 3;
    if (ch < 6) STAGE(ch + 2, (ch + 2) % 3);          // issue 2-ahead, then compute
    const u16* Ac = As[cur];
    const u16* Bc = Bs[cur];
#pragma unroll
    for (int kk = 0; kk < 2; ++kk) {
      s16x8 af[4], bfr[4];
#pragma unroll
      for (int mt = 0; mt < 4; ++mt) {
        int m = mh + mt * 16 + lane16;
        int cs = (kk * 4 + q) ^ (m & 7);
        af[mt] = *(const s16x8*)(Ac + m * 64 + cs * 8);
      }
#pragma unroll
      for (int nt = 0; nt < 4; ++nt) {
        int n = nh + nt * 16 + lane16;
        int cs = (kk * 4 + q) ^ (n & 7);
        bfr[nt] = *(const s16x8*)(Bc + n * 64 + cs * 8);
      }
#pragma unroll
      for (int mt = 0; mt < 4; ++mt)
#pragma unroll
        for (int nt = 0; nt < 4; ++nt)
          acc[mt][nt] = __builtin_amdgcn_mfma_f32_16x16x32_bf16(af[mt], bfr[nt], acc[mt][nt], 0, 0, 0);
    }
    if (ch < 7) {
      if (ch < 6) { asm volatile("s_waitcnt vmcnt(6)" ::: "memory"); }  // next buf ready
      else        { asm volatile("s_waitcnt vmcnt(0)" ::: "memory"); }  // last buf
      __builtin_amdgcn_s_barrier();
      asm volatile("" ::: "memory");
    }
  }
#undef STAGE
  // epilogue: subtract med[n]*colsum[d]
#pragma unroll
  for (int nt = 0; nt < 4; ++nt) {
    int n = nb * 256 + nh + nt * 16 + lane16;
    int b = n >> 5, v = n & 31;
    float mv = med[n];
    float* obase = out + (size_t)b * (Dn * Cn) + v;
#pragma unroll
    for (int mt = 0; mt < 4; ++mt) {
      int d0 = mb * 128 + mh + mt * 16 + q * 4;
#pragma unroll
      for (int r = 0; r < 4; ++r)
        obase[(size_t)(d0 + r) * Cn] = acc[mt][nt][r] - mv * csum[d0 + r];
    }
  }
}

extern "C" void kernel_launch(void* const* d_in, const int* in_sizes, int n_in,
                              void* d_out, int out_size, void* d_ws, size_t ws_size,
                              hipStream_t stream) {
  const float* x   = (const float*)d_in[0];
  const float* emb = (const float*)d_in[3];
  const float* Wg  = (const float*)d_in[4];
  const float* We  = (const float*)d_in[6];
  float* out = (float*)d_out;
  char* ws = (char*)d_ws;
  float* med   = (float*)(ws);                         // 64 KB
  float* cpart = (float*)(ws + 65536);                 // 16 KB
  u16*   WmT   = (u16*)(ws + 65536 + 16384);           // 512 KB
  u16*   xbf   = (u16*)(ws + 65536 + 16384 + 524288);  // 16.8 MB

  hipLaunchKernelGGL(k_pw,   dim3(1088), dim3(256), 0, stream,
                     x, emb, Wg, We, med, xbf, WmT, cpart);
  hipLaunchKernelGGL(k_gemm, dim3(256),  dim3(512), 0, stream,
                     WmT, xbf, med, cpart, out);
}